// Round 2
// baseline (140.487 us; speedup 1.0000x reference)
//
#include <hip/hip_runtime.h>
#include <stdint.h>

#define B_ 32
#define S_ 32
#define P_ 2048
#define J_ 32
#define I_ 16

// ---------- bf16 helpers (RNE pack, cheap unpack) ----------
__device__ inline uint32_t bfpack(float a, float b) {
    uint32_t ua = __float_as_uint(a);
    uint32_t ub = __float_as_uint(b);
    ua += 0x7fffu + ((ua >> 16) & 1u);   // round-to-nearest-even
    ub += 0x7fffu + ((ub >> 16) & 1u);
    return (ua >> 16) | (ub & 0xffff0000u);
}
__device__ inline float bflo(uint32_t d) { return __uint_as_float(d << 16); }
__device__ inline float bfhi(uint32_t d) { return __uint_as_float(d & 0xffff0000u); }

__device__ inline float dot4(float4 a, float4 b) {
    return fmaf(a.x, b.x, fmaf(a.y, b.y, fmaf(a.z, b.z, a.w * b.w)));
}

// =====================================================================
// Kernel 1: u_hat[b,s,p,j] = sum_i W[s,p,j,i] * X[b,p,i]
// Stored as bf16 pairs (dword k of a row = j=2k | j=2k+1<<16).
// Thread = (s, p, j-PAIR): 8 float4 of W (32 VGPR) -> ~6 waves/SIMD
// occupancy (was 4 at j-quad/120 VGPR). Explicit one-ahead X prefetch
// pipelines the L2-latency X load under the 32-FMA body.
// =====================================================================
__global__ __launch_bounds__(256) void uhat_kernel(
        const float* __restrict__ W, const float* __restrict__ X,
        uint32_t* __restrict__ U) {
    const int tid = threadIdx.x;
    const int jg  = tid & 15;         // j-pair index: j = 2*jg, 2*jg+1
    const int pl  = tid >> 4;         // 0..15
    const int p   = blockIdx.x * 16 + pl;
    const int s   = blockIdx.y;

    // W rows 2jg, 2jg+1: 128B contiguous per thread
    const float4* wp = reinterpret_cast<const float4*>(
        W + (((size_t)s * P_ + p) * J_ + jg * 2) * I_);
    float4 w[8];
    #pragma unroll
    for (int q = 0; q < 8; ++q) w[q] = wp[q];

    const float4* xp = reinterpret_cast<const float4*>(X) + (size_t)p * 4;
    uint32_t* up = U + ((size_t)s * P_ + p) * (J_ / 2) + jg;

    // software pipeline: x holds iteration b, prefetch b+1 before compute
    float4 x0 = xp[0], x1 = xp[1], x2 = xp[2], x3 = xp[3];
    #pragma unroll 4
    for (int b = 0; b < B_; ++b) {
        float4 y0 = x0, y1 = x1, y2 = x2, y3 = x3;
        if (b + 1 < B_) {
            const float4* xn = xp + (size_t)(b + 1) * (P_ * 4);
            x0 = xn[0]; x1 = xn[1]; x2 = xn[2]; x3 = xn[3];
        }
        float a0 = dot4(w[0], y0) + dot4(w[1], y1) + dot4(w[2], y2) + dot4(w[3], y3);
        float a1 = dot4(w[4], y0) + dot4(w[5], y1) + dot4(w[6], y2) + dot4(w[7], y3);
        up[(size_t)b * (S_ * P_ * (J_ / 2))] = bfpack(a0, a1);
    }
}

// ---------- split-butterfly wave reduction of a 32-vector ----------
template <int MASK, int HALF>
__device__ inline void red_level(float* red, int lane) {
    const bool hi = (lane & MASK) != 0;
    #pragma unroll
    for (int k = 0; k < HALF; ++k) {
        float send = hi ? red[k] : red[k + HALF];
        float recv = __shfl_xor(send, MASK, 64);
        red[k] = (hi ? red[k + HALF] : red[k]) + recv;
    }
}

// =====================================================================
// Kernel 2: dynamic routing. One 1024-thread block per (b,s).
// Thread owns rows p0=2*tid, p1=2*tid+1 of u_hat (bf16-packed, 32 VGPR).
// All 3 iterations run with u_hat in registers (single HBM read).
// =====================================================================
__global__ __launch_bounds__(1024) void routing_kernel(
        const uint32_t* __restrict__ U, float* __restrict__ out) {
    const int tid  = threadIdx.x;
    const int lane = tid & 63;
    const int wid  = tid >> 6;            // 0..15
    const int bs   = blockIdx.x;          // b*S_ + s

    __shared__ float sred[16 * 32];       // per-wave 32-vector partials
    __shared__ __align__(16) float vlds[32];
    __shared__ float scal[32];            // [0..15] max partials, [16..31] sum partials

    // load my 2 rows: 32 dwords = 128B contiguous
    const uint32_t* ub = U + (size_t)bs * P_ * (J_ / 2) + (size_t)tid * 32;
    uint32_t a[32];
    #pragma unroll
    for (int k = 0; k < 8; ++k) {
        uint4 t = reinterpret_cast<const uint4*>(ub)[k];
        a[k * 4 + 0] = t.x; a[k * 4 + 1] = t.y;
        a[k * 4 + 2] = t.z; a[k * 4 + 3] = t.w;
    }
    // a[0..15] = row p0 (j pairs), a[16..31] = row p1

    float bp0 = 0.0f, bp1 = 0.0f;         // routing logits for my two p's

    for (int it = 0; it < 3; ++it) {
        // ---- c = softmax(b) over p ----
        float c0, c1;
        if (it == 0) {
            c0 = c1 = 1.0f / 2048.0f;     // softmax of zeros, exact
        } else {
            float m = fmaxf(bp0, bp1);
            #pragma unroll
            for (int msk = 32; msk >= 1; msk >>= 1)
                m = fmaxf(m, __shfl_xor(m, msk, 64));
            if (lane == 0) scal[wid] = m;
            __syncthreads();
            m = scal[0];
            #pragma unroll
            for (int w2 = 1; w2 < 16; ++w2) m = fmaxf(m, scal[w2]);
            float e0 = __expf(bp0 - m);
            float e1 = __expf(bp1 - m);
            float zs = e0 + e1;
            #pragma unroll
            for (int msk = 32; msk >= 1; msk >>= 1)
                zs += __shfl_xor(zs, msk, 64);
            if (lane == 0) scal[16 + wid] = zs;
            __syncthreads();
            float Z = 0.0f;
            #pragma unroll
            for (int w2 = 0; w2 < 16; ++w2) Z += scal[16 + w2];
            float invZ = 1.0f / Z;
            c0 = e0 * invZ;
            c1 = e1 * invZ;
        }

        // ---- per-thread partial s_j = c0*u[p0][j] + c1*u[p1][j] ----
        float red[32];
        #pragma unroll
        for (int k = 0; k < 16; ++k) {
            uint32_t d0 = a[k], d1 = a[16 + k];
            red[2 * k]     = fmaf(c0, bflo(d0), c1 * bflo(d1));
            red[2 * k + 1] = fmaf(c0, bfhi(d0), c1 * bfhi(d1));
        }
        // ---- wave reduce-scatter (31 shfl total) ----
        red_level<32, 16>(red, lane);
        red_level<16, 8>(red, lane);
        red_level<8, 4>(red, lane);
        red_level<4, 2>(red, lane);
        red_level<2, 1>(red, lane);
        red[0] += __shfl_xor(red[0], 1, 64);   // lane holds s_{lane>>1} wave-sum
        if ((lane & 1) == 0) sred[wid * 32 + (lane >> 1)] = red[0];
        __syncthreads();

        // ---- cross-wave finalize + squash (first 32 threads) ----
        if (tid < 32) {
            float s = 0.0f;
            #pragma unroll
            for (int w2 = 0; w2 < 16; ++w2) s += sred[w2 * 32 + tid];
            float sq = s * s;
            #pragma unroll
            for (int msk = 16; msk >= 1; msk >>= 1)
                sq += __shfl_xor(sq, msk, 64);
            float n = sqrtf(sq);
            float scale = sq / ((1.0f + sq) * (n + 1e-7f));
            float v = s * scale;
            vlds[tid] = v;
            if (it == 2) out[(size_t)bs * J_ + tid] = v;
        }
        __syncthreads();

        // ---- agreement + logit update (not needed after last iter) ----
        if (it < 2) {
            const float2* vl2 = reinterpret_cast<const float2*>(vlds);
            float ag0 = 0.0f, ag1 = 0.0f;
            #pragma unroll
            for (int k = 0; k < 16; ++k) {
                float2 vk = vl2[k];               // v[2k], v[2k+1] (LDS broadcast)
                uint32_t d0 = a[k], d1 = a[16 + k];
                ag0 = fmaf(vk.x, bflo(d0), ag0);
                ag0 = fmaf(vk.y, bfhi(d0), ag0);
                ag1 = fmaf(vk.x, bflo(d1), ag1);
                ag1 = fmaf(vk.y, bfhi(d1), ag1);
            }
            bp0 += ag0;
            bp1 += ag1;
        }
    }
}

extern "C" void kernel_launch(void* const* d_in, const int* in_sizes, int n_in,
                              void* d_out, int out_size, void* d_ws, size_t ws_size,
                              hipStream_t stream) {
    (void)in_sizes; (void)n_in; (void)out_size;
    const float* X = (const float*)d_in[0];        // [B,P,I] fp32
    const float* W = (const float*)d_in[1];        // [S,P,J,I] fp32
    float* out     = (float*)d_out;                // [B,S,J] fp32
    uint32_t* U    = (uint32_t*)d_ws;              // bf16 u_hat [B,S,P,J/2 dwords]

    const size_t need = (size_t)B_ * S_ * P_ * J_ * 2;  // 128 MiB
    if (ws_size < need) return;  // cannot run without scratch

    dim3 g1(P_ / 16, S_);
    uhat_kernel<<<g1, 256, 0, stream>>>(W, X, U);
    routing_kernel<<<B_ * S_, 1024, 0, stream>>>(U, out);
}

// Round 3
// 111.690 us; speedup vs baseline: 1.2578x; 1.2578x over previous
//
#include <hip/hip_runtime.h>
#include <stdint.h>

#define B_ 32
#define S_ 32
#define P_ 2048
#define J_ 32
#define I_ 16

// ---------- bf16 helpers (RNE pack, cheap unpack) ----------
__device__ inline uint32_t bfpack(float a, float b) {
    uint32_t ua = __float_as_uint(a);
    uint32_t ub = __float_as_uint(b);
    ua += 0x7fffu + ((ua >> 16) & 1u);   // round-to-nearest-even
    ub += 0x7fffu + ((ub >> 16) & 1u);
    return (ua >> 16) | (ub & 0xffff0000u);
}
__device__ inline float bflo(uint32_t d) { return __uint_as_float(d << 16); }
__device__ inline float bfhi(uint32_t d) { return __uint_as_float(d & 0xffff0000u); }

__device__ inline float dot4(float4 a, float4 b) {
    return fmaf(a.x, b.x, fmaf(a.y, b.y, fmaf(a.z, b.z, a.w * b.w)));
}

// =====================================================================
// Kernel 1: u_hat[b,s,p,j] = sum_i W[s,p,j,i] * X[b,p,i]
// R2 post-mortem: VMEM-request-path bound (168 VMEM instrs/wave; VALUBusy
// pinned at 24% independent of occupancy). Fix: stage the block's X slab
// (32 b x 16 p x 64B = 32KB) in LDS once (8 coalesced loads + 8 ds_writes
// per thread), so the b-loop does ZERO global loads — only broadcast
// ds_read_b128 (lgkm pipe) + 32 FMA + 1 coalesced store.
// Per-wave VMEM: 8 W + 8 stage + 32 stores = 48 (was 168).
// =====================================================================
__global__ __launch_bounds__(256) void uhat_kernel(
        const float* __restrict__ W, const float* __restrict__ X,
        uint32_t* __restrict__ U) {
    const int tid = threadIdx.x;
    const int jg  = tid & 15;         // j-pair index: j = 2*jg, 2*jg+1
    const int pl  = tid >> 4;         // 0..15
    const int p   = blockIdx.x * 16 + pl;
    const int s   = blockIdx.y;

    // [b][pl][q] linear, 32 KiB -> 5 blocks/CU by LDS.
    // Loop reads: 4 distinct pl per wave -> banks (16*pl+4q)%32 -> 2-way (free).
    __shared__ float4 xs[32 * 64];

    // W rows 2jg, 2jg+1: 128B contiguous per thread (issue these first;
    // they stream from HBM/L3 and overlap the X staging below)
    const float4* wp = reinterpret_cast<const float4*>(
        W + (((size_t)s * P_ + p) * J_ + jg * 2) * I_);
    float4 w[8];
    #pragma unroll
    for (int q = 0; q < 8; ++q) w[q] = wp[q];

    // ---- stage X slab: flat f = t + k*256, f = b*64 + pl*4 + q ----
    // Each k-chunk of 64 consecutive f is one b: fully coalesced 1KB loads.
    const float4* X4 = reinterpret_cast<const float4*>(X);
    const size_t xbase = (size_t)blockIdx.x * 64;   // float4 offset of p-chunk
    #pragma unroll
    for (int k = 0; k < 8; ++k) {
        int f = tid + k * 256;
        int b = f >> 6;
        int r = f & 63;
        xs[f] = X4[(size_t)b * (P_ * 4) + xbase + r];
    }
    __syncthreads();

    uint32_t* up = U + ((size_t)s * P_ + p) * (J_ / 2) + jg;
    const float4* xrow = xs + pl * 4;

    #pragma unroll 4
    for (int b = 0; b < B_; ++b) {
        float4 y0 = xrow[b * 64 + 0];
        float4 y1 = xrow[b * 64 + 1];
        float4 y2 = xrow[b * 64 + 2];
        float4 y3 = xrow[b * 64 + 3];
        float a0 = dot4(w[0], y0) + dot4(w[1], y1) + dot4(w[2], y2) + dot4(w[3], y3);
        float a1 = dot4(w[4], y0) + dot4(w[5], y1) + dot4(w[6], y2) + dot4(w[7], y3);
        up[(size_t)b * (S_ * P_ * (J_ / 2))] = bfpack(a0, a1);
    }
}

// ---------- split-butterfly wave reduction of a 32-vector ----------
template <int MASK, int HALF>
__device__ inline void red_level(float* red, int lane) {
    const bool hi = (lane & MASK) != 0;
    #pragma unroll
    for (int k = 0; k < HALF; ++k) {
        float send = hi ? red[k] : red[k + HALF];
        float recv = __shfl_xor(send, MASK, 64);
        red[k] = (hi ? red[k + HALF] : red[k]) + recv;
    }
}

// =====================================================================
// Kernel 2: dynamic routing. One 1024-thread block per (b,s).
// Thread owns rows p0=2*tid, p1=2*tid+1 of u_hat (bf16-packed, 32 VGPR).
// All 3 iterations run with u_hat in registers (single HBM read).
// =====================================================================
__global__ __launch_bounds__(1024) void routing_kernel(
        const uint32_t* __restrict__ U, float* __restrict__ out) {
    const int tid  = threadIdx.x;
    const int lane = tid & 63;
    const int wid  = tid >> 6;            // 0..15
    const int bs   = blockIdx.x;          // b*S_ + s

    __shared__ float sred[16 * 32];       // per-wave 32-vector partials
    __shared__ __align__(16) float vlds[32];
    __shared__ float scal[32];            // [0..15] max partials, [16..31] sum partials

    // load my 2 rows: 32 dwords = 128B contiguous
    const uint32_t* ub = U + (size_t)bs * P_ * (J_ / 2) + (size_t)tid * 32;
    uint32_t a[32];
    #pragma unroll
    for (int k = 0; k < 8; ++k) {
        uint4 t = reinterpret_cast<const uint4*>(ub)[k];
        a[k * 4 + 0] = t.x; a[k * 4 + 1] = t.y;
        a[k * 4 + 2] = t.z; a[k * 4 + 3] = t.w;
    }
    // a[0..15] = row p0 (j pairs), a[16..31] = row p1

    float bp0 = 0.0f, bp1 = 0.0f;         // routing logits for my two p's

    for (int it = 0; it < 3; ++it) {
        // ---- c = softmax(b) over p ----
        float c0, c1;
        if (it == 0) {
            c0 = c1 = 1.0f / 2048.0f;     // softmax of zeros, exact
        } else {
            float m = fmaxf(bp0, bp1);
            #pragma unroll
            for (int msk = 32; msk >= 1; msk >>= 1)
                m = fmaxf(m, __shfl_xor(m, msk, 64));
            if (lane == 0) scal[wid] = m;
            __syncthreads();
            m = scal[0];
            #pragma unroll
            for (int w2 = 1; w2 < 16; ++w2) m = fmaxf(m, scal[w2]);
            float e0 = __expf(bp0 - m);
            float e1 = __expf(bp1 - m);
            float zs = e0 + e1;
            #pragma unroll
            for (int msk = 32; msk >= 1; msk >>= 1)
                zs += __shfl_xor(zs, msk, 64);
            if (lane == 0) scal[16 + wid] = zs;
            __syncthreads();
            float Z = 0.0f;
            #pragma unroll
            for (int w2 = 0; w2 < 16; ++w2) Z += scal[16 + w2];
            float invZ = 1.0f / Z;
            c0 = e0 * invZ;
            c1 = e1 * invZ;
        }

        // ---- per-thread partial s_j = c0*u[p0][j] + c1*u[p1][j] ----
        float red[32];
        #pragma unroll
        for (int k = 0; k < 16; ++k) {
            uint32_t d0 = a[k], d1 = a[16 + k];
            red[2 * k]     = fmaf(c0, bflo(d0), c1 * bflo(d1));
            red[2 * k + 1] = fmaf(c0, bfhi(d0), c1 * bfhi(d1));
        }
        // ---- wave reduce-scatter (31 shfl total) ----
        red_level<32, 16>(red, lane);
        red_level<16, 8>(red, lane);
        red_level<8, 4>(red, lane);
        red_level<4, 2>(red, lane);
        red_level<2, 1>(red, lane);
        red[0] += __shfl_xor(red[0], 1, 64);   // lane holds s_{lane>>1} wave-sum
        if ((lane & 1) == 0) sred[wid * 32 + (lane >> 1)] = red[0];
        __syncthreads();

        // ---- cross-wave finalize + squash (first 32 threads) ----
        if (tid < 32) {
            float s = 0.0f;
            #pragma unroll
            for (int w2 = 0; w2 < 16; ++w2) s += sred[w2 * 32 + tid];
            float sq = s * s;
            #pragma unroll
            for (int msk = 16; msk >= 1; msk >>= 1)
                sq += __shfl_xor(sq, msk, 64);
            float n = sqrtf(sq);
            float scale = sq / ((1.0f + sq) * (n + 1e-7f));
            float v = s * scale;
            vlds[tid] = v;
            if (it == 2) out[(size_t)bs * J_ + tid] = v;
        }
        __syncthreads();

        // ---- agreement + logit update (not needed after last iter) ----
        if (it < 2) {
            const float2* vl2 = reinterpret_cast<const float2*>(vlds);
            float ag0 = 0.0f, ag1 = 0.0f;
            #pragma unroll
            for (int k = 0; k < 16; ++k) {
                float2 vk = vl2[k];               // v[2k], v[2k+1] (LDS broadcast)
                uint32_t d0 = a[k], d1 = a[16 + k];
                ag0 = fmaf(vk.x, bflo(d0), ag0);
                ag0 = fmaf(vk.y, bfhi(d0), ag0);
                ag1 = fmaf(vk.x, bflo(d1), ag1);
                ag1 = fmaf(vk.y, bfhi(d1), ag1);
            }
            bp0 += ag0;
            bp1 += ag1;
        }
    }
}

extern "C" void kernel_launch(void* const* d_in, const int* in_sizes, int n_in,
                              void* d_out, int out_size, void* d_ws, size_t ws_size,
                              hipStream_t stream) {
    (void)in_sizes; (void)n_in; (void)out_size;
    const float* X = (const float*)d_in[0];        // [B,P,I] fp32
    const float* W = (const float*)d_in[1];        // [S,P,J,I] fp32
    float* out     = (float*)d_out;                // [B,S,J] fp32
    uint32_t* U    = (uint32_t*)d_ws;              // bf16 u_hat [B,S,P,J/2 dwords]

    const size_t need = (size_t)B_ * S_ * P_ * J_ * 2;  // 128 MiB
    if (ws_size < need) return;  // cannot run without scratch

    dim3 g1(P_ / 16, S_);
    uhat_kernel<<<g1, 256, 0, stream>>>(W, X, U);
    routing_kernel<<<B_ * S_, 1024, 0, stream>>>(U, out);
}

// Round 5
// 105.102 us; speedup vs baseline: 1.3367x; 1.0627x over previous
//
#include <hip/hip_runtime.h>
#include <stdint.h>

#define B_ 32
#define S_ 32
#define P_ 2048
#define J_ 32
#define I_ 16

typedef _Float16 half8_t __attribute__((ext_vector_type(8)));
typedef float f32x16 __attribute__((ext_vector_type(16)));

// fp16 unpack helpers (U is stored as packed fp16 pairs in dwords)
__device__ inline float f16lo(uint32_t d) {
    return (float)__builtin_bit_cast(_Float16, (unsigned short)(d & 0xffffu));
}
__device__ inline float f16hi(uint32_t d) {
    return (float)__builtin_bit_cast(_Float16, (unsigned short)(d >> 16));
}

// =====================================================================
// Kernel 1 (MFMA): per (s,p), C[b=32, j=32] = X[b,i=16] . W[j,i=16]^T
// == one v_mfma_f32_32x32x16_f16. Block = 256 thr (4 waves) covers
// (s, 16 p). C (f32) -> fp16 -> LDS transpose slab [b][p_local][j]
// (granule-XOR swizzled) -> 128B-dense global stores to U[b][s][p][j].
// R3 post-mortem: fp32 FMA issue (~2650 cyc/wave) was co-dominant with
// HBM; MFMA removes ~95% of VALU work -> HBM-bound.
// Accuracy: fp16 RNE (2^-11) on W,X + RNE fp16 store beats bf16 (2^-9).
// =====================================================================
__global__ __launch_bounds__(256) void uhat_kernel(
        const float* __restrict__ W, const float* __restrict__ X,
        uint16_t* __restrict__ U) {
    const int tid  = threadIdx.x;
    const int lane = tid & 63;
    const int wave = tid >> 6;
    const int l31  = lane & 31;
    const int lhi  = lane >> 5;       // 0/1
    const int s    = blockIdx.y;
    const int p0   = blockIdx.x * 16;

    __shared__ uint16_t cs[16384];    // 32 KiB: [b][p_local][j] fp16, swizzled

    #pragma unroll
    for (int t = 0; t < 4; ++t) {
        const int pl = wave * 4 + t;
        const int p  = p0 + pl;

        // B-frag: W[s,p, j=l31, i=lhi*8 .. +7]  (32B contiguous per lane)
        const float* wr = W + (((size_t)s * P_ + p) * J_ + l31) * I_ + lhi * 8;
        float4 w0 = *reinterpret_cast<const float4*>(wr);
        float4 w1 = *reinterpret_cast<const float4*>(wr + 4);
        // A-frag: X[b=l31, p, i=lhi*8 .. +7]
        const float* xr = X + ((size_t)l31 * P_ + p) * I_ + lhi * 8;
        float4 x0 = *reinterpret_cast<const float4*>(xr);
        float4 x1 = *reinterpret_cast<const float4*>(xr + 4);

        half8_t A, Bf;
        A[0] = (_Float16)x0.x; A[1] = (_Float16)x0.y;
        A[2] = (_Float16)x0.z; A[3] = (_Float16)x0.w;
        A[4] = (_Float16)x1.x; A[5] = (_Float16)x1.y;
        A[6] = (_Float16)x1.z; A[7] = (_Float16)x1.w;
        Bf[0] = (_Float16)w0.x; Bf[1] = (_Float16)w0.y;
        Bf[2] = (_Float16)w0.z; Bf[3] = (_Float16)w0.w;
        Bf[4] = (_Float16)w1.x; Bf[5] = (_Float16)w1.y;
        Bf[6] = (_Float16)w1.z; Bf[7] = (_Float16)w1.w;

        f32x16 acc = {};
        acc = __builtin_amdgcn_mfma_f32_32x32x16_f16(A, Bf, acc, 0, 0, 0);

        // C/D layout (HW-verified): col j = l31, row b = (r&3)+8*(r>>2)+4*lhi
        const int swz = ((pl >> 1) & 7) << 4;   // granule XOR key for this p
        #pragma unroll
        for (int r = 0; r < 16; ++r) {
            const int b = (r & 3) + 8 * (r >> 2) + 4 * lhi;
            const int byteaddr = (b * 1024 + pl * 64 + l31 * 2) ^ swz;
            _Float16 h = (_Float16)acc[r];      // RNE
            cs[byteaddr >> 1] = __builtin_bit_cast(unsigned short, h);
        }
    }
    __syncthreads();

    // Coalesced store: thread (b=tid>>3, sub=tid&7), 8 rounds of 16B.
    // Global: U[b][s][p0..p0+15][j] -> 1KB contiguous per b.
    const int b   = tid >> 3;
    const int sub = tid & 7;
    uint16_t* gb = U + (((size_t)b * S_ + s) * P_ + p0) * J_;
    #pragma unroll
    for (int k = 0; k < 8; ++k) {
        const int lb = b * 1024 + k * 128 + ((sub ^ k) * 16);   // swizzled read
        uint4 v = *reinterpret_cast<const uint4*>(
            reinterpret_cast<const char*>(cs) + lb);
        *reinterpret_cast<uint4*>(
            reinterpret_cast<char*>(gb) + k * 128 + sub * 16) = v;
    }
}

// ---------- split-butterfly wave reduction of a 32-vector ----------
template <int MASK, int HALF>
__device__ inline void red_level(float* red, int lane) {
    const bool hi = (lane & MASK) != 0;
    #pragma unroll
    for (int k = 0; k < HALF; ++k) {
        float send = hi ? red[k] : red[k + HALF];
        float recv = __shfl_xor(send, MASK, 64);
        red[k] = (hi ? red[k + HALF] : red[k]) + recv;
    }
}

// =====================================================================
// Kernel 2: dynamic routing. One 1024-thread block per (b,s).
// Thread owns rows p0=2*tid, p1=2*tid+1 of u_hat (fp16-packed, 32 VGPR).
// All 3 iterations run with u_hat in registers (single HBM read).
// =====================================================================
__global__ __launch_bounds__(1024) void routing_kernel(
        const uint32_t* __restrict__ U, float* __restrict__ out) {
    const int tid  = threadIdx.x;
    const int lane = tid & 63;
    const int wid  = tid >> 6;            // 0..15
    const int bs   = blockIdx.x;          // b*S_ + s

    __shared__ float sred[16 * 32];       // per-wave 32-vector partials
    __shared__ __align__(16) float vlds[32];
    __shared__ float scal[32];            // [0..15] max partials, [16..31] sum partials

    // load my 2 rows: 32 dwords = 128B contiguous
    const uint32_t* ub = U + (size_t)bs * P_ * (J_ / 2) + (size_t)tid * 32;
    uint32_t a[32];
    #pragma unroll
    for (int k = 0; k < 8; ++k) {
        uint4 t = reinterpret_cast<const uint4*>(ub)[k];
        a[k * 4 + 0] = t.x; a[k * 4 + 1] = t.y;
        a[k * 4 + 2] = t.z; a[k * 4 + 3] = t.w;
    }
    // a[0..15] = row p0 (j pairs), a[16..31] = row p1

    float bp0 = 0.0f, bp1 = 0.0f;         // routing logits for my two p's

    for (int it = 0; it < 3; ++it) {
        // ---- c = softmax(b) over p ----
        float c0, c1;
        if (it == 0) {
            c0 = c1 = 1.0f / 2048.0f;     // softmax of zeros, exact
        } else {
            float m = fmaxf(bp0, bp1);
            #pragma unroll
            for (int msk = 32; msk >= 1; msk >>= 1)
                m = fmaxf(m, __shfl_xor(m, msk, 64));
            if (lane == 0) scal[wid] = m;
            __syncthreads();
            m = scal[0];
            #pragma unroll
            for (int w2 = 1; w2 < 16; ++w2) m = fmaxf(m, scal[w2]);
            float e0 = __expf(bp0 - m);
            float e1 = __expf(bp1 - m);
            float zs = e0 + e1;
            #pragma unroll
            for (int msk = 32; msk >= 1; msk >>= 1)
                zs += __shfl_xor(zs, msk, 64);
            if (lane == 0) scal[16 + wid] = zs;
            __syncthreads();
            float Z = 0.0f;
            #pragma unroll
            for (int w2 = 0; w2 < 16; ++w2) Z += scal[16 + w2];
            float invZ = 1.0f / Z;
            c0 = e0 * invZ;
            c1 = e1 * invZ;
        }

        // ---- per-thread partial s_j = c0*u[p0][j] + c1*u[p1][j] ----
        float red[32];
        #pragma unroll
        for (int k = 0; k < 16; ++k) {
            uint32_t d0 = a[k], d1 = a[16 + k];
            red[2 * k]     = fmaf(c0, f16lo(d0), c1 * f16lo(d1));
            red[2 * k + 1] = fmaf(c0, f16hi(d0), c1 * f16hi(d1));
        }
        // ---- wave reduce-scatter (31 shfl total) ----
        red_level<32, 16>(red, lane);
        red_level<16, 8>(red, lane);
        red_level<8, 4>(red, lane);
        red_level<4, 2>(red, lane);
        red_level<2, 1>(red, lane);
        red[0] += __shfl_xor(red[0], 1, 64);   // lane holds s_{lane>>1} wave-sum
        if ((lane & 1) == 0) sred[wid * 32 + (lane >> 1)] = red[0];
        __syncthreads();

        // ---- cross-wave finalize + squash (first 32 threads) ----
        if (tid < 32) {
            float s = 0.0f;
            #pragma unroll
            for (int w2 = 0; w2 < 16; ++w2) s += sred[w2 * 32 + tid];
            float sq = s * s;
            #pragma unroll
            for (int msk = 16; msk >= 1; msk >>= 1)
                sq += __shfl_xor(sq, msk, 64);
            float n = sqrtf(sq);
            float scale = sq / ((1.0f + sq) * (n + 1e-7f));
            float v = s * scale;
            vlds[tid] = v;
            if (it == 2) out[(size_t)bs * J_ + tid] = v;
        }
        __syncthreads();

        // ---- agreement + logit update (not needed after last iter) ----
        if (it < 2) {
            const float2* vl2 = reinterpret_cast<const float2*>(vlds);
            float ag0 = 0.0f, ag1 = 0.0f;
            #pragma unroll
            for (int k = 0; k < 16; ++k) {
                float2 vk = vl2[k];               // v[2k], v[2k+1] (LDS broadcast)
                uint32_t d0 = a[k], d1 = a[16 + k];
                ag0 = fmaf(vk.x, f16lo(d0), ag0);
                ag0 = fmaf(vk.y, f16hi(d0), ag0);
                ag1 = fmaf(vk.x, f16lo(d1), ag1);
                ag1 = fmaf(vk.y, f16hi(d1), ag1);
            }
            bp0 += ag0;
            bp1 += ag1;
        }
    }
}

extern "C" void kernel_launch(void* const* d_in, const int* in_sizes, int n_in,
                              void* d_out, int out_size, void* d_ws, size_t ws_size,
                              hipStream_t stream) {
    (void)in_sizes; (void)n_in; (void)out_size;
    const float* X = (const float*)d_in[0];        // [B,P,I] fp32
    const float* W = (const float*)d_in[1];        // [S,P,J,I] fp32
    float* out     = (float*)d_out;                // [B,S,J] fp32
    uint16_t* U    = (uint16_t*)d_ws;              // fp16 u_hat [B,S,P,J]

    const size_t need = (size_t)B_ * S_ * P_ * J_ * 2;  // 128 MiB
    if (ws_size < need) return;  // cannot run without scratch

    dim3 g1(P_ / 16, S_);
    uhat_kernel<<<g1, 256, 0, stream>>>(W, X, U);
    routing_kernel<<<B_ * S_, 1024, 0, stream>>>((const uint32_t*)U, out);
}